// Round 1
// baseline (328.823 us; speedup 1.0000x reference)
//
#include <hip/hip_runtime.h>

// Problem constants (from reference): x [64, 3, 512, 512] f32, shifts [64, 2] i32
#define BATCH 64
#define CHAN  3
#define HH    512
#define WW    512
#define W4    (WW / 4)   // 128 float4 per row

// out[b,c,h,w] = x[b,c,(h - s0) mod H, (w - s1) mod W]
// One thread per output float4: coalesced 16B stores; reads are contiguous
// within a (rotated) 512-float row, so they coalesce at cacheline granularity.
__global__ __launch_bounds__(256) void roll_kernel(
    const float* __restrict__ x,
    const int*   __restrict__ shifts,
    float4*      __restrict__ out)
{
    const int idx = blockIdx.x * blockDim.x + threadIdx.x;  // float4 index
    // Layout: idx = ((bc * H) + h) * W4 + w4
    const int w4 = idx & (W4 - 1);
    const int h  = (idx >> 7) & (HH - 1);
    const int bc = idx >> 16;          // b*CHAN + c  (H*W4 = 65536 = 2^16)
    const int b  = bc / 3;

    const int s0 = shifts[2 * b];
    const int s1 = shifts[2 * b + 1];

    const int hs = (h - s0) & (HH - 1);        // two's-complement & = mod 512
    const int w0 = (w4 << 2) - s1;             // may be negative, mask per elem

    const float* src = x + ((size_t)bc * HH + hs) * WW;

    float4 v;
    v.x = src[(w0    ) & (WW - 1)];
    v.y = src[(w0 + 1) & (WW - 1)];
    v.z = src[(w0 + 2) & (WW - 1)];
    v.w = src[(w0 + 3) & (WW - 1)];

    out[idx] = v;
}

extern "C" void kernel_launch(void* const* d_in, const int* in_sizes, int n_in,
                              void* d_out, int out_size, void* d_ws, size_t ws_size,
                              hipStream_t stream)
{
    const float* x      = (const float*)d_in[0];
    const int*   shifts = (const int*)d_in[1];
    float4*      out    = (float4*)d_out;

    const int total4 = BATCH * CHAN * HH * W4;   // 12,582,912
    const int block  = 256;
    const int grid   = total4 / block;           // 49,152

    roll_kernel<<<grid, block, 0, stream>>>(x, shifts, out);
}

// Round 2
// 316.375 us; speedup vs baseline: 1.0393x; 1.0393x over previous
//
#include <hip/hip_runtime.h>

// x: [64, 3, 512, 512] f32, shifts: [64, 2] i32
// out[b,c,h,w] = x[b,c,(h - s0) & 511, (w - s1) & 511]
#define BATCH 64
#define CHAN  3
#define HH    512
#define WW    512
#define W4    (WW / 4)   // 128 float4 per row

// Each block handles 2 full rows (2 x 128 float4).
// Stage rotated source rows in LDS with aligned float4 loads, then resolve the
// W-rotation with two adjacent-quad LDS reads + a wave-uniform funnel select.
// All global traffic is aligned 16B/lane; LDS access pattern is consecutive
// 16B/lane (conflict-free b128).
__global__ __launch_bounds__(256) void roll_lds_kernel(
    const float4* __restrict__ x,
    const int*    __restrict__ shifts,
    float4*       __restrict__ out)
{
    __shared__ float4 lds[2 * W4];   // 4 KB

    const int tid    = threadIdx.x;
    const int r      = tid >> 7;            // row within block (0/1)
    const int w4     = tid & (W4 - 1);      // quad index within row
    const int row_id = blockIdx.x * 2 + r;  // global row: bc*512 + h
    const int bc     = row_id >> 9;
    const int h      = row_id & (HH - 1);
    const int b      = bc / CHAN;

    const int s0 = shifts[2 * b];
    const int s1 = shifts[2 * b + 1];

    // H-rotation: fetch source row (h - s0) mod 512, aligned float4.
    const int hs = (h - s0) & (HH - 1);
    lds[tid] = x[((size_t)bc * HH + hs) * W4 + w4];
    __syncthreads();

    // W-rotation: out[4*w4 + k] = row[(4*w4 + k + d) mod 512], d = (-s1) mod 512
    const int d  = (-s1) & (WW - 1);
    const int qd = d >> 2;       // whole-quad shift
    const int rd = d & 3;        // intra-quad shift (uniform per block)
    const int qa = (w4 + qd) & (W4 - 1);
    const int qb = (qa + 1) & (W4 - 1);
    const float4 A = lds[(r << 7) + qa];
    const float4 B = lds[(r << 7) + qb];

    float4 o;
    if      (rd == 0) o = A;
    else if (rd == 1) o = make_float4(A.y, A.z, A.w, B.x);
    else if (rd == 2) o = make_float4(A.z, A.w, B.x, B.y);
    else              o = make_float4(A.w, B.x, B.y, B.z);

    out[row_id * W4 + w4] = o;
}

extern "C" void kernel_launch(void* const* d_in, const int* in_sizes, int n_in,
                              void* d_out, int out_size, void* d_ws, size_t ws_size,
                              hipStream_t stream)
{
    const float4* x      = (const float4*)d_in[0];
    const int*    shifts = (const int*)d_in[1];
    float4*       out    = (float4*)d_out;

    const int rows  = BATCH * CHAN * HH;   // 98304
    const int grid  = rows / 2;            // 49152 blocks, 2 rows each
    const int block = 256;

    roll_lds_kernel<<<grid, block, 0, stream>>>(x, shifts, out);
}